// Round 2
// baseline (823.157 us; speedup 1.0000x reference)
//
#include <hip/hip_runtime.h>

#define N_  128
#define IC_ 3
#define OC_ 16
#define H_  256
#define W_  256
#define OH_ 254
#define OW_ 254

typedef float v2f __attribute__((ext_vector_type(2)));

// Packed double-safe mish: mish(x) = x*(t-1)/(t+1), t = (1+e^x)^2.
// Overflow guard via min-clamp on t (packable): t=inf -> 1e30 -> ratio ~= 1 -> mish(x)=x.
__device__ __forceinline__ v2f mish2(v2f x) {
    v2f xe = x * 1.44269504088896340f;           // v_pk_mul
    v2f e;
    e.x = __builtin_amdgcn_exp2f(xe.x);          // trans
    e.y = __builtin_amdgcn_exp2f(xe.y);
    v2f p = e + 1.0f;
    v2f t = p * p;
    v2f clampv = {1e30f, 1e30f};
    t = __builtin_elementwise_min(t, clampv);
    v2f num = (t - 1.0f) * x;
    v2f den = t + 1.0f;
    v2f r;
    r.x = __builtin_amdgcn_rcpf(den.x);          // trans
    r.y = __builtin_amdgcn_rcpf(den.y);
    return num * r;
}

// Repack weights [oc][ic][kh][kw] -> [r][oc] (r = ic*9+kh*3+kw): for a fixed tap r
// the 16 oc are contiguous -> uniform-address loads scalarize (s_load), oc-pairs are
// even-aligned SGPR pairs feeding v_pk_fma_f32.
__global__ void repack_w(const float* __restrict__ w, float* __restrict__ pw) {
    int i = threadIdx.x;
    if (i < 432) {
        int oc = i / 27;
        int r  = i - oc * 27;
        pw[r * 16 + oc] = w[i];
    }
}

__global__ __launch_bounds__(256) void conv_mish_kernel(
    const float* __restrict__ x, const float* __restrict__ pw,
    const float* __restrict__ bias, float* __restrict__ out)
{
    int t  = threadIdx.x;
    int l  = t & 63;                 // lane: 4 output cols each
    int wv_ = t >> 6;                // wave: 1 output row each
    int oh = blockIdx.x * 4 + wv_;
    if (oh >= OH_) return;           // block 63: waves 2,3 idle
    int n  = blockIdx.y;
    int c0 = 4 * l;                  // cols c0..c0+3 (lane 63: 252,253 valid only)
    int c4 = (l == 63) ? 248 : c0 + 4;  // clamp tail load in-bounds (values unused)

    // acc[c][q]: output col c0+c, oc pair (2q, 2q+1)
    v2f acc[4][8];
    const v2f* bq = (const v2f*)bias;            // uniform -> s_load
    #pragma unroll
    for (int q = 0; q < 8; ++q) {
        v2f b = bq[q];
        acc[0][q] = b; acc[1][q] = b; acc[2][q] = b; acc[3][q] = b;
    }

    const float* xb = x + (size_t)n * (IC_ * H_ * W_);
    const v2f*   wt = (const v2f*)pw;            // uniform indices -> s_load

    // prefetch input row for s=0 (ic=0, kh=0)
    const float* rp0 = xb + (size_t)oh * W_;
    float4 a  = *(const float4*)(rp0 + c0);      // 16B aligned
    float2 b2 = *(const float2*)(rp0 + c4);

    #pragma unroll 1
    for (int s = 0; s < 9; ++s) {
        float in0 = a.x, in1 = a.y, in2 = a.z, in3 = a.w, in4 = b2.x, in5 = b2.y;
        if (s < 8) {                              // 1-deep prefetch of next row
            int s1 = s + 1;
            int ic = s1 / 3, kh = s1 - ic * 3;
            const float* rp = xb + ic * (H_ * W_) + (size_t)(oh + kh) * W_;
            a  = *(const float4*)(rp + c0);
            b2 = *(const float2*)(rp + c4);
        }
        float in[6] = {in0, in1, in2, in3, in4, in5};
        #pragma unroll
        for (int kw = 0; kw < 3; ++kw) {
            #pragma unroll
            for (int q = 0; q < 8; ++q) {
                v2f w2 = wt[s * 24 + kw * 8 + q];     // SGPR pair
                acc[0][q] += w2 * (v2f){in[kw + 0], in[kw + 0]};  // v_pk_fma_f32
                acc[1][q] += w2 * (v2f){in[kw + 1], in[kw + 1]};
                acc[2][q] += w2 * (v2f){in[kw + 2], in[kw + 2]};
                acc[3][q] += w2 * (v2f){in[kw + 3], in[kw + 3]};
            }
        }
    }

    float* ob = out + (size_t)n * (OC_ * OH_ * OW_) + (size_t)oh * OW_ + c0;
    bool hi_ok = (l < 63);           // lane 63: cols 254,255 are out of range
    #pragma unroll
    for (int q = 0; q < 8; ++q) {
        v2f m0 = mish2(mish2(acc[0][q]));
        v2f m1 = mish2(mish2(acc[1][q]));
        v2f m2 = mish2(mish2(acc[2][q]));
        v2f m3 = mish2(mish2(acc[3][q]));
        float* p0 = ob + (size_t)(2 * q)     * (OH_ * OW_);
        float* p1 = ob + (size_t)(2 * q + 1) * (OH_ * OW_);
        __builtin_nontemporal_store((v2f){m0.x, m1.x}, (v2f*)p0);       // cols c0,c0+1
        __builtin_nontemporal_store((v2f){m0.y, m1.y}, (v2f*)p1);
        if (hi_ok) {
            __builtin_nontemporal_store((v2f){m2.x, m3.x}, (v2f*)(p0 + 2));  // cols c0+2,c0+3
            __builtin_nontemporal_store((v2f){m2.y, m3.y}, (v2f*)(p1 + 2));
        }
    }
}

extern "C" void kernel_launch(void* const* d_in, const int* in_sizes, int n_in,
                              void* d_out, int out_size, void* d_ws, size_t ws_size,
                              hipStream_t stream) {
    const float* x = (const float*)d_in[0];
    const float* w = (const float*)d_in[1];
    const float* b = (const float*)d_in[2];
    float* pw = (float*)d_ws;                       // 432 floats = 1728 B
    repack_w<<<dim3(1), dim3(512), 0, stream>>>(w, pw);
    dim3 grid((OH_ + 3) / 4, N_);   // (64, 128)
    dim3 block(256);
    conv_mish_kernel<<<grid, block, 0, stream>>>(x, pw, b, (float*)d_out);
}

// Round 3
// 645.862 us; speedup vs baseline: 1.2745x; 1.2745x over previous
//
#include <hip/hip_runtime.h>

#define N_  128
#define IC_ 3
#define OC_ 16
#define H_  256
#define W_  256
#define OH_ 254
#define OW_ 254

typedef float v2f __attribute__((ext_vector_type(2)));

// Packed double-safe mish: mish(x) = x*(t-1)/(t+1), t = (1+e^x)^2.
// Overflow guard via min-clamp on t (packable): t=inf -> 1e30 -> ratio ~= 1 -> mish(x)=x.
__device__ __forceinline__ v2f mish2(v2f x) {
    v2f xe = x * 1.44269504088896340f;           // v_pk_mul
    v2f e;
    e.x = __builtin_amdgcn_exp2f(xe.x);          // trans
    e.y = __builtin_amdgcn_exp2f(xe.y);
    v2f p = e + 1.0f;
    v2f t = p * p;
    v2f clampv = {1e30f, 1e30f};
    t = __builtin_elementwise_min(t, clampv);
    v2f num = (t - 1.0f) * x;
    v2f den = t + 1.0f;
    v2f r;
    r.x = __builtin_amdgcn_rcpf(den.x);          // trans
    r.y = __builtin_amdgcn_rcpf(den.y);
    return num * r;
}

// Repack weights [oc][ic][kh][kw] -> [r][oc] (r = ic*9+kh*3+kw): for a fixed tap r
// the 16 oc are contiguous -> uniform-address loads scalarize (s_load), oc-pairs are
// even-aligned SGPR pairs feeding v_pk_fma_f32.
__global__ void repack_w(const float* __restrict__ w, float* __restrict__ pw) {
    int i = threadIdx.x;
    if (i < 432) {
        int oc = i / 27;
        int r  = i - oc * 27;
        pw[r * 16 + oc] = w[i];
    }
}

__global__ __launch_bounds__(256) void conv_mish_kernel(
    const float* __restrict__ x, const float* __restrict__ pw,
    const float* __restrict__ bias, float* __restrict__ out)
{
    int t   = threadIdx.x;
    int l   = t & 63;                // lane: 4 output cols each
    int wv_ = t >> 6;                // wave: 1 output row each
    int oh  = blockIdx.x * 4 + wv_;
    if (oh >= OH_) return;           // last block: waves 2,3 idle
    int n   = blockIdx.y;
    int c0  = 4 * l;                 // cols c0..c0+3 (lane 63: 252,253 valid only)
    int c4  = (l == 63) ? 248 : c0 + 4;  // clamp tail load in-bounds (values unused)

    // acc[c][q]: output col c0+c, oc pair (2q, 2q+1)
    v2f acc[4][8];
    const v2f* bq = (const v2f*)bias;            // uniform -> s_load
    #pragma unroll
    for (int q = 0; q < 8; ++q) {
        v2f b = bq[q];
        acc[0][q] = b; acc[1][q] = b; acc[2][q] = b; acc[3][q] = b;
    }

    const float* xb = x + (size_t)n * (IC_ * H_ * W_);
    const v2f*   wt = (const v2f*)pw;            // uniform indices -> s_load

    // double-buffered ic-group prefetch: 3 rows (kh=0..2) in flight per group
    float4 a[3]; float2 b2[3];
    {
        const float* rp = xb + (size_t)oh * W_;  // ic = 0
        a[0] = *(const float4*)(rp + c0);            b2[0] = *(const float2*)(rp + c4);
        a[1] = *(const float4*)(rp + W_ + c0);       b2[1] = *(const float2*)(rp + W_ + c4);
        a[2] = *(const float4*)(rp + 2 * W_ + c0);   b2[2] = *(const float2*)(rp + 2 * W_ + c4);
    }

    #pragma unroll 1
    for (int ic = 0; ic < 3; ++ic) {
        // capture current group into scalars (frees a[]/b2[] for the next prefetch)
        float in[3][6];
        #pragma unroll
        for (int kh = 0; kh < 3; ++kh) {
            in[kh][0] = a[kh].x; in[kh][1] = a[kh].y; in[kh][2] = a[kh].z;
            in[kh][3] = a[kh].w; in[kh][4] = b2[kh].x; in[kh][5] = b2[kh].y;
        }
        if (ic < 2) {                             // issue next ic-group loads early
            const float* rp = xb + (ic + 1) * (H_ * W_) + (size_t)oh * W_;
            a[0] = *(const float4*)(rp + c0);            b2[0] = *(const float2*)(rp + c4);
            a[1] = *(const float4*)(rp + W_ + c0);       b2[1] = *(const float2*)(rp + W_ + c4);
            a[2] = *(const float4*)(rp + 2 * W_ + c0);   b2[2] = *(const float2*)(rp + 2 * W_ + c4);
        }
        // 288 v_pk_fma_f32 on the current group — covers the prefetch latency
        #pragma unroll
        for (int kh = 0; kh < 3; ++kh) {
            #pragma unroll
            for (int kw = 0; kw < 3; ++kw) {
                int r = ic * 9 + kh * 3 + kw;     // tap index; ic*72B s_load offsets
                #pragma unroll
                for (int q = 0; q < 8; ++q) {
                    v2f w2 = wt[r * 8 + q];       // SGPR pair
                    acc[0][q] += w2 * (v2f){in[kh][kw + 0], in[kh][kw + 0]};
                    acc[1][q] += w2 * (v2f){in[kh][kw + 1], in[kh][kw + 1]};
                    acc[2][q] += w2 * (v2f){in[kh][kw + 2], in[kh][kw + 2]};
                    acc[3][q] += w2 * (v2f){in[kh][kw + 3], in[kh][kw + 3]};
                }
            }
        }
    }

    float* ob = out + (size_t)n * (OC_ * OH_ * OW_) + (size_t)oh * OW_ + c0;
    bool hi_ok = (l < 63);           // lane 63: cols 254,255 are out of range
    #pragma unroll
    for (int q = 0; q < 8; ++q) {
        v2f m0 = mish2(mish2(acc[0][q]));
        v2f m1 = mish2(mish2(acc[1][q]));
        v2f m2 = mish2(mish2(acc[2][q]));
        v2f m3 = mish2(mish2(acc[3][q]));
        float* p0 = ob + (size_t)(2 * q)     * (OH_ * OW_);
        float* p1 = ob + (size_t)(2 * q + 1) * (OH_ * OW_);
        // plain cached stores: L2 merges the complementary half-sector writes,
        // so HBM sees full lines (nt stores here caused 1.86x write amplification)
        *(v2f*)p0 = (v2f){m0.x, m1.x};            // oc=2q,   cols c0..c0+1
        *(v2f*)p1 = (v2f){m0.y, m1.y};            // oc=2q+1, cols c0..c0+1
        if (hi_ok) {
            *(v2f*)(p0 + 2) = (v2f){m2.x, m3.x};  // cols c0+2..c0+3
            *(v2f*)(p1 + 2) = (v2f){m2.y, m3.y};
        }
    }
}

extern "C" void kernel_launch(void* const* d_in, const int* in_sizes, int n_in,
                              void* d_out, int out_size, void* d_ws, size_t ws_size,
                              hipStream_t stream) {
    const float* x = (const float*)d_in[0];
    const float* w = (const float*)d_in[1];
    const float* b = (const float*)d_in[2];
    float* pw = (float*)d_ws;                       // 432 floats = 1728 B
    repack_w<<<dim3(1), dim3(512), 0, stream>>>(w, pw);
    dim3 grid((OH_ + 3) / 4, N_);   // (64, 128)
    dim3 block(256);
    conv_mish_kernel<<<grid, block, 0, stream>>>(x, pw, b, (float*)d_out);
}